// Round 10
// baseline (3159.864 us; speedup 1.0000x reference)
//
#include <hip/hip_runtime.h>

using short8 = __attribute__((ext_vector_type(8))) short;
using f32x4  = __attribute__((ext_vector_type(4))) float;

#define NT     512
#define NBATCH 64
#define NN     1024
#define NIN    24
#define NGRP   8
#define BPG    8                        // batches per group
#define NWG    128                      // 2x oversubscription for XCD claiming
#define OBS_BUF_ELEMS (NGRP * BPG * NN) // 64K u16 per ping-pong buffer
#define SCOPE_AGENT __HIP_MEMORY_SCOPE_AGENT
#define POLL_CAP 20000  // fast-poll guard; falls back to proven agent-atomic poll

// ws: [0,512) arr u32[128] | [512,576) xcd_cnt u32[16] | [576,580) ovf_cnt
//     [640,704) grp_slow u32[16] | [1024,1536) flags 8x32 u16
//     [4096,8192) zero region | [8192,+256KB) obs 2 x [8 grp][8 rows][1024] bf16

__device__ __forceinline__ unsigned short f2bf(float x) {
  union { float f; unsigned u; } v; v.f = x;
  return (unsigned short)((v.u + 0x7FFFu + ((v.u >> 16) & 1u)) >> 16);
}
__device__ __forceinline__ f32x4 MF(short8 a, short8 b, f32x4 c) {
  return __builtin_amdgcn_mfma_f32_16x16x32_bf16(a, b, c, 0, 0, 0);
}

// 128 WGs x 512 thr (8 waves); 64 become active. Each block claims a slot on
// ITS OWN XCD (atomicAdd on xcd_cnt[XCC_ID]): first 8 blocks per XCD form that
// XCD's group -> co-located by construction. Group g owns batches [8g,8g+8);
// slot owns neurons [128*slot,+128). Deficit groups get overflow blocks in the
// proven slow (L3 agent-atomic) mode; surplus exits.
// R9: __launch_bounds__(512, 1) — (512,2) capped VGPR at 128 and silently
// SPILLED the 128-VGPR persistent W-fragment array to scratch, which was the
// ~6us/step floor in R6-R8. 1 block/CU -> 256 VGPR cap -> W stays in registers.
__global__ __launch_bounds__(512, 1) void rnn_step_all(
    const float* __restrict__ u, const float* __restrict__ r0,
    const float* __restrict__ W, const float* __restrict__ Bm,
    const float* __restrict__ tau, const float* __restrict__ ds,
    float* __restrict__ out,
    unsigned* __restrict__ arr, unsigned* __restrict__ xcd_cnt,
    unsigned* __restrict__ ovf_cnt, unsigned* __restrict__ grp_slow,
    unsigned short* __restrict__ sflags, unsigned short* __restrict__ zreg,
    unsigned short* __restrict__ obs)
{
  const int tid  = threadIdx.x;
  const int wave = tid >> 6;
  const int lane = tid & 63;
  const int bid  = blockIdx.x;
  const int lr = lane & 15, lg = lane >> 4;

  __shared__ unsigned s_g, s_slot, s_mode, s_fast;  // mode 0=native 1=fallback 2=idle 3=pending

  auto grid_barrier = [&](unsigned epoch) {
    if (tid == 0)
      __hip_atomic_store(&arr[bid], epoch, __ATOMIC_RELEASE, SCOPE_AGENT);
    if (wave == 0) {
      for (;;) {
        unsigned a = __hip_atomic_load(&arr[lane],      __ATOMIC_RELAXED, SCOPE_AGENT);
        unsigned b = __hip_atomic_load(&arr[64 + lane], __ATOMIC_RELAXED, SCOPE_AGENT);
        if (__all((int)(a >= epoch && b >= epoch))) break;
        __builtin_amdgcn_s_sleep(1);
      }
    }
    __syncthreads();
    __builtin_amdgcn_fence(__ATOMIC_ACQUIRE, "agent");
  };

  // ---- claim a slot on my XCD ----
  unsigned myxcc;
  asm volatile("s_getreg_b32 %0, hwreg(HW_REG_XCC_ID)" : "=s"(myxcc));
  if (tid == 0) {
    unsigned c = __hip_atomic_fetch_add(&xcd_cnt[myxcc & 7], 1u,
                                        __ATOMIC_RELAXED, SCOPE_AGENT);
    if (c < 8) { s_g = myxcc & 7; s_slot = c; s_mode = 0; }
    else {
      s_g = __hip_atomic_fetch_add(ovf_cnt, 1u, __ATOMIC_RELAXED, SCOPE_AGENT);
      s_slot = 0; s_mode = 3;
    }
  }
  __syncthreads();
  grid_barrier(1);   // all claims visible

  // ---- overflow blocks resolve deficits deterministically ----
  if (s_mode == 3) {
    if (tid == 0) {
      unsigned k = s_g, base = 0, mode = 2, g = 0, slot = 0;
      for (int gg = 0; gg < 8; ++gg) {
        unsigned c = __hip_atomic_load(&xcd_cnt[gg], __ATOMIC_RELAXED, SCOPE_AGENT);
        unsigned have = c < 8 ? c : 8;
        unsigned def  = 8 - have;
        if (k < base + def) { g = gg; slot = have + (k - base); mode = 1; break; }
        base += def;
      }
      s_g = g; s_slot = slot; s_mode = mode;
      if (mode == 1)
        __hip_atomic_store(&grp_slow[g], 1u, __ATOMIC_RELAXED, SCOPE_AGENT);
    }
    __syncthreads();
  }
  grid_barrier(2);   // grp_slow visible
  if (s_mode == 2) return;  // surplus blocks exit

  if (tid == 0) {
    unsigned sl = __hip_atomic_load(&grp_slow[s_g], __ATOMIC_RELAXED, SCOPE_AGENT);
    s_fast = (s_mode == 0 && sl == 0u) ? 1u : 0u;
  }
  __syncthreads();
  const int  g    = (int)s_g;
  const int  slot = (int)s_slot;
  const bool fast = s_fast != 0;

  const int b0 = g * BPG;
  const int i  = slot * 128 + wave * 16 + lr;   // this lane's neuron

  unsigned short* gf = sflags + g * 32;

  // ---- persistent W fragments: B[k][col] = W[i0+col][kb*32+k]*sign ----
  short8 wf[32];
#pragma unroll
  for (int kb = 0; kb < 32; ++kb) {
    const int j0 = kb * 32 + lg * 8;
    const float* wp = W + (size_t)i * NN + j0;
    f32x4 w0 = *(const f32x4*)(wp);
    f32x4 w1 = *(const f32x4*)(wp + 4);
    f32x4 s0 = *(const f32x4*)(ds + j0);
    f32x4 s1 = *(const f32x4*)(ds + j0 + 4);
    short8 f;
    f[0] = (short)f2bf(w0[0] * s0[0]); f[1] = (short)f2bf(w0[1] * s0[1]);
    f[2] = (short)f2bf(w0[2] * s0[2]); f[3] = (short)f2bf(w0[3] * s0[3]);
    f[4] = (short)f2bf(w1[0] * s1[0]); f[5] = (short)f2bf(w1[1] * s1[1]);
    f[6] = (short)f2bf(w1[2] * s1[2]); f[7] = (short)f2bf(w1[3] * s1[3]);
    wf[kb] = f;
  }
  short8 bin;
#pragma unroll
  for (int e = 0; e < 8; ++e) {
    const int m = lg * 8 + e;
    bin[e] = (short)f2bf(m < NIN ? Bm[(size_t)i * NIN + m] : 0.0f);
  }
  const float itau = 1.0f / tau[i];

  unsigned short* owbuf0 = obs + g * BPG * NN;
  unsigned short* owbuf1 = owbuf0 + OBS_BUF_ELEMS;

  // ---- init r; publish obs buf0; group barrier epoch 1 ----
  f32x4 r = {0.f, 0.f, 0.f, 0.f};
  if (lg < 2) {
#pragma unroll
    for (int q = 0; q < 4; ++q) {
      const int row = lg * 4 + q;
      r[q] = r0[(size_t)(b0 + row) * NN + i];
      const unsigned short v = f2bf(r[q] > 0.0f ? r[q] : 0.0f);
      if (fast) owbuf0[row * NN + i] = v;
      else      __hip_atomic_store(&owbuf0[row * NN + i], v,
                                   __ATOMIC_RELAXED, SCOPE_AGENT);
    }
  }
  asm volatile("s_waitcnt vmcnt(0)" ::: "memory");
  __syncthreads();
  if (tid == 0) {
    if (fast) *(volatile unsigned short*)&gf[slot] = (unsigned short)1;
    else      __hip_atomic_store(&gf[slot], (unsigned short)1,
                                 __ATOMIC_RELAXED, SCOPE_AGENT);
  }

  const float* up_base = u + (size_t)(b0 + lr) * NT * NIN;
  f32x4 up0 = {0.f,0.f,0.f,0.f}, up1 = {0.f,0.f,0.f,0.f};
  if (lr < 8 && lg < 3) {
    up0 = *(const f32x4*)(up_base + lg * 8);
    up1 = *(const f32x4*)(up_base + lg * 8 + 4);
  }

  auto group_wait = [&](unsigned tgt) {
    if (wave == 0) {
      if (fast) {
        int guard = 0;
        for (;;) {
          asm volatile("buffer_inv" ::: "memory");   // L1 inv -> read L2 fresh
          unsigned x = *(volatile const unsigned short*)(gf + (lane & 7));
          if (__all((int)(x >= tgt))) break;
          if (++guard > POLL_CAP) {   // proven-correct fallback, never hang
            unsigned y;
            do {
              y = __hip_atomic_load(&gf[lane & 7], __ATOMIC_RELAXED, SCOPE_AGENT);
            } while (!__all((int)(y >= tgt)));
            asm volatile("buffer_inv" ::: "memory");
            break;
          }
        }
      } else {
        for (;;) {
          unsigned x = __hip_atomic_load(&gf[lane & 7], __ATOMIC_RELAXED, SCOPE_AGENT);
          if (__all((int)(x >= tgt))) break;
          __builtin_amdgcn_s_sleep(1);
        }
      }
    }
    __syncthreads();
    if (!fast) __builtin_amdgcn_fence(__ATOMIC_ACQUIRE, "agent");
  };

  group_wait(1);

  // per-lane A base: rows >= 8 of the 16x16 A tile read the zero region
  const unsigned short* ab0 = (lr < 8) ? owbuf0 + lr * NN + lg * 8 : zreg + lg * 8;
  const unsigned short* ab1 = (lr < 8) ? ab0 + OBS_BUF_ELEMS : ab0;

  for (int t = 0; t < NT; ++t) {
    const unsigned short* ab = (t & 1) ? ab1 : ab0;
    unsigned short*       ow = (t & 1) ? owbuf0 : owbuf1;

    f32x4 acc  = {0.f, 0.f, 0.f, 0.f};
    f32x4 acc1 = {0.f, 0.f, 0.f, 0.f};

    // input term: A[row=lr][m] = u[b0+lr][t][m], zero-padded
    short8 ua;
    ua[0] = (short)f2bf(up0[0]); ua[1] = (short)f2bf(up0[1]);
    ua[2] = (short)f2bf(up0[2]); ua[3] = (short)f2bf(up0[3]);
    ua[4] = (short)f2bf(up1[0]); ua[5] = (short)f2bf(up1[1]);
    ua[6] = (short)f2bf(up1[2]); ua[7] = (short)f2bf(up1[3]);
    if (lr >= 8 || lg >= 3) ua = short8{0,0,0,0,0,0,0,0};
    acc = MF(ua, bin, acc);

    // recurrent GEMM: plain cacheable loads (L1 shared by the CU's 8 waves;
    // freshness guaranteed by the poll's buffer_inv on the successful iter)
#pragma unroll
    for (int kb = 0; kb < 32; kb += 2) {
      short8 a0 = *(const short8*)(ab + kb * 32);
      short8 a1 = *(const short8*)(ab + kb * 32 + 32);
      acc  = MF(a0, wf[kb],     acc);
      acc1 = MF(a1, wf[kb + 1], acc1);
    }

    // state update
    f32x4 rv;
#pragma unroll
    for (int q = 0; q < 4; ++q) {
      const float pre = acc[q] + acc1[q];
      const float act = 60.0f / (1.0f + expf(8.4f - 0.28f * pre)); // 30*(1+tanh(.14x-4.2))
      rv[q] = r[q] + (0.1f * (act - r[q])) * itau;
      r[q]  = rv[q];
    }

    if (t != NT - 1) {
      // publish obs; release: vmcnt(0) -> barrier -> one flag store (epoch t+2)
      if (lg < 2) {
#pragma unroll
        for (int q = 0; q < 4; ++q) {
          const unsigned short v = f2bf(rv[q] > 0.0f ? rv[q] : 0.0f);
          if (fast) ow[(lg * 4 + q) * NN + i] = v;
          else      __hip_atomic_store(&ow[(lg * 4 + q) * NN + i], v,
                                       __ATOMIC_RELAXED, SCOPE_AGENT);
        }
      }
      asm volatile("s_waitcnt vmcnt(0)" ::: "memory");
      __syncthreads();
      if (tid == 0) {
        if (fast) *(volatile unsigned short*)&gf[slot] = (unsigned short)(t + 2);
        else      __hip_atomic_store(&gf[slot], (unsigned short)(t + 2),
                                     __ATOMIC_RELAXED, SCOPE_AGENT);
      }

      // off-critical-path: u prefetch + out stores overlap the poll
      if (lr < 8 && lg < 3) {
        const float* up = up_base + (t + 1) * NIN + lg * 8;
        up0 = *(const f32x4*)(up);
        up1 = *(const f32x4*)(up + 4);
      }
      if (lg < 2) {
#pragma unroll
        for (int q = 0; q < 4; ++q)
          __builtin_nontemporal_store(rv[q],
              &out[((size_t)(b0 + lg * 4 + q) * NT + t) * NN + i]);
      }

      group_wait((unsigned)(t + 2));
    } else {
      if (lg < 2) {
#pragma unroll
        for (int q = 0; q < 4; ++q)
          __builtin_nontemporal_store(rv[q],
              &out[((size_t)(b0 + lg * 4 + q) * NT + t) * NN + i]);
      }
    }
  }

  // r_final
  if (lg < 2) {
#pragma unroll
    for (int q = 0; q < 4; ++q)
      out[(size_t)NBATCH * NT * NN + (size_t)(b0 + lg * 4 + q) * NN + i] = r[q];
  }
}

extern "C" void kernel_launch(void* const* d_in, const int* in_sizes, int n_in,
                              void* d_out, int out_size, void* d_ws, size_t ws_size,
                              hipStream_t stream) {
  const float* u   = (const float*)d_in[0];
  const float* r0  = (const float*)d_in[1];
  const float* W   = (const float*)d_in[2];
  const float* Bm  = (const float*)d_in[3];
  const float* tau = (const float*)d_in[4];
  const float* ds  = (const float*)d_in[5];
  float* out = (float*)d_out;

  unsigned*       arr      = (unsigned*)d_ws;
  unsigned*       xcd_cnt  = (unsigned*)((char*)d_ws + 512);
  unsigned*       ovf_cnt  = (unsigned*)((char*)d_ws + 576);
  unsigned*       grp_slow = (unsigned*)((char*)d_ws + 640);
  unsigned short* sflags   = (unsigned short*)((char*)d_ws + 1024);
  unsigned short* zreg     = (unsigned short*)((char*)d_ws + 4096);
  unsigned short* obs      = (unsigned short*)((char*)d_ws + 8192);

  // zero all control state every call (incl. graph replays -> deterministic)
  hipMemsetAsync(d_ws, 0, 8192, stream);

  rnn_step_all<<<dim3(NWG), dim3(512), 0, stream>>>(u, r0, W, Bm, tau, ds, out,
                                                    arr, xcd_cnt, ovf_cnt, grp_slow,
                                                    sflags, zreg, obs);
}

// Round 11
// 3082.528 us; speedup vs baseline: 1.0251x; 1.0251x over previous
//
#include <hip/hip_runtime.h>

using short8 = __attribute__((ext_vector_type(8))) short;
using f32x4  = __attribute__((ext_vector_type(4))) float;

#define NT     512
#define NBATCH 64
#define NN     1024
#define NIN    24
#define NGRP   8
#define BPG    8                        // batches per group
#define NWG    128                      // 2x oversubscription for XCD claiming
#define OBS_BUF_ELEMS (NGRP * BPG * NN) // 64K u16 per ping-pong buffer
#define SCOPE_AGENT __HIP_MEMORY_SCOPE_AGENT

// ws: [0,512) arr u32[128] | [512,576) xcd_cnt u32[16] | [576,580) ovf_cnt
//     [640,704) grp_slow u32[16] | [1024,1536) flags 8x32 u16
//     [4096,8192) zero region | [8192,+256KB) obs 2 x [8 grp][8 rows][1024] bf16

__device__ __forceinline__ unsigned short f2bf(float x) {
  union { float f; unsigned u; } v; v.f = x;
  return (unsigned short)((v.u + 0x7FFFu + ((v.u >> 16) & 1u)) >> 16);
}
__device__ __forceinline__ f32x4 MF(short8 a, short8 b, f32x4 c) {
  return __builtin_amdgcn_mfma_f32_16x16x32_bf16(a, b, c, 0, 0, 0);
}
// out store: sc1 -> bypass L2 (don't evict obs), ack at L3
__device__ __forceinline__ void st_out(float* p, float v) {
  asm volatile("global_store_dword %0, %1, off sc1" :: "v"(p), "v"(v) : "memory");
}

// 128 WGs x 512 thr (8 waves); 64 become active. Each block claims a slot on
// ITS OWN XCD (atomicAdd on xcd_cnt[XCC_ID]): first 8 blocks per XCD form that
// XCD's group -> co-located by construction. Group g owns batches [8g,8g+8);
// slot owns neurons [128*slot,+128). Deficit groups get overflow blocks in
// slow (L3 obs) mode; surplus exits.
// R10 sync: flags ALWAYS via agent atomics (sc1/L3, deadlock-free, no cap, no
// per-iter buffer_inv). After detect: fast -> one L1 buffer_inv (obs fresh in
// shared XCD L2); slow -> agent acquire fence. out stores sc1 (no L2 pollution)
// issued after the flag store so they drain during the poll, not the release.
__global__ __launch_bounds__(512, 1) void rnn_step_all(
    const float* __restrict__ u, const float* __restrict__ r0,
    const float* __restrict__ W, const float* __restrict__ Bm,
    const float* __restrict__ tau, const float* __restrict__ ds,
    float* __restrict__ out,
    unsigned* __restrict__ arr, unsigned* __restrict__ xcd_cnt,
    unsigned* __restrict__ ovf_cnt, unsigned* __restrict__ grp_slow,
    unsigned short* __restrict__ sflags, unsigned short* __restrict__ zreg,
    unsigned short* __restrict__ obs)
{
  const int tid  = threadIdx.x;
  const int wave = tid >> 6;
  const int lane = tid & 63;
  const int bid  = blockIdx.x;
  const int lr = lane & 15, lg = lane >> 4;

  __shared__ unsigned s_g, s_slot, s_mode, s_fast;  // mode 0=native 1=fallback 2=idle 3=pending

  auto grid_barrier = [&](unsigned epoch) {
    if (tid == 0)
      __hip_atomic_store(&arr[bid], epoch, __ATOMIC_RELEASE, SCOPE_AGENT);
    if (wave == 0) {
      for (;;) {
        unsigned a = __hip_atomic_load(&arr[lane],      __ATOMIC_RELAXED, SCOPE_AGENT);
        unsigned b = __hip_atomic_load(&arr[64 + lane], __ATOMIC_RELAXED, SCOPE_AGENT);
        if (__all((int)(a >= epoch && b >= epoch))) break;
        __builtin_amdgcn_s_sleep(1);
      }
    }
    __syncthreads();
    __builtin_amdgcn_fence(__ATOMIC_ACQUIRE, "agent");
  };

  // ---- claim a slot on my XCD ----
  unsigned myxcc;
  asm volatile("s_getreg_b32 %0, hwreg(HW_REG_XCC_ID)" : "=s"(myxcc));
  if (tid == 0) {
    unsigned c = __hip_atomic_fetch_add(&xcd_cnt[myxcc & 7], 1u,
                                        __ATOMIC_RELAXED, SCOPE_AGENT);
    if (c < 8) { s_g = myxcc & 7; s_slot = c; s_mode = 0; }
    else {
      s_g = __hip_atomic_fetch_add(ovf_cnt, 1u, __ATOMIC_RELAXED, SCOPE_AGENT);
      s_slot = 0; s_mode = 3;
    }
  }
  __syncthreads();
  grid_barrier(1);   // all claims visible

  // ---- overflow blocks resolve deficits deterministically ----
  if (s_mode == 3) {
    if (tid == 0) {
      unsigned k = s_g, base = 0, mode = 2, g = 0, slot = 0;
      for (int gg = 0; gg < 8; ++gg) {
        unsigned c = __hip_atomic_load(&xcd_cnt[gg], __ATOMIC_RELAXED, SCOPE_AGENT);
        unsigned have = c < 8 ? c : 8;
        unsigned def  = 8 - have;
        if (k < base + def) { g = gg; slot = have + (k - base); mode = 1; break; }
        base += def;
      }
      s_g = g; s_slot = slot; s_mode = mode;
      if (mode == 1)
        __hip_atomic_store(&grp_slow[g], 1u, __ATOMIC_RELAXED, SCOPE_AGENT);
    }
    __syncthreads();
  }
  grid_barrier(2);   // grp_slow visible
  if (s_mode == 2) return;  // surplus blocks exit

  if (tid == 0) {
    unsigned sl = __hip_atomic_load(&grp_slow[s_g], __ATOMIC_RELAXED, SCOPE_AGENT);
    s_fast = (s_mode == 0 && sl == 0u) ? 1u : 0u;
  }
  __syncthreads();
  const int  g    = (int)s_g;
  const int  slot = (int)s_slot;
  const bool fast = s_fast != 0;

  const int b0 = g * BPG;
  const int i  = slot * 128 + wave * 16 + lr;   // this lane's neuron

  unsigned short* gf = sflags + g * 32;

  // ---- persistent W fragments: B[k][col] = W[i0+col][kb*32+k]*sign ----
  short8 wf[32];
#pragma unroll
  for (int kb = 0; kb < 32; ++kb) {
    const int j0 = kb * 32 + lg * 8;
    const float* wp = W + (size_t)i * NN + j0;
    f32x4 w0 = *(const f32x4*)(wp);
    f32x4 w1 = *(const f32x4*)(wp + 4);
    f32x4 s0 = *(const f32x4*)(ds + j0);
    f32x4 s1 = *(const f32x4*)(ds + j0 + 4);
    short8 f;
    f[0] = (short)f2bf(w0[0] * s0[0]); f[1] = (short)f2bf(w0[1] * s0[1]);
    f[2] = (short)f2bf(w0[2] * s0[2]); f[3] = (short)f2bf(w0[3] * s0[3]);
    f[4] = (short)f2bf(w1[0] * s1[0]); f[5] = (short)f2bf(w1[1] * s1[1]);
    f[6] = (short)f2bf(w1[2] * s1[2]); f[7] = (short)f2bf(w1[3] * s1[3]);
    wf[kb] = f;
  }
  short8 bin;
#pragma unroll
  for (int e = 0; e < 8; ++e) {
    const int m = lg * 8 + e;
    bin[e] = (short)f2bf(m < NIN ? Bm[(size_t)i * NIN + m] : 0.0f);
  }
  const float itau = 1.0f / tau[i];

  unsigned short* owbuf0 = obs + g * BPG * NN;
  unsigned short* owbuf1 = owbuf0 + OBS_BUF_ELEMS;

  // ---- init r; publish obs buf0; flag epoch 1 ----
  f32x4 r = {0.f, 0.f, 0.f, 0.f};
  if (lg < 2) {
#pragma unroll
    for (int q = 0; q < 4; ++q) {
      const int row = lg * 4 + q;
      r[q] = r0[(size_t)(b0 + row) * NN + i];
      const unsigned short v = f2bf(r[q] > 0.0f ? r[q] : 0.0f);
      if (fast) owbuf0[row * NN + i] = v;
      else      __hip_atomic_store(&owbuf0[row * NN + i], v,
                                   __ATOMIC_RELAXED, SCOPE_AGENT);
    }
  }
  asm volatile("s_waitcnt vmcnt(0)" ::: "memory");
  __syncthreads();
  if (tid == 0)
    __hip_atomic_store(&gf[slot], (unsigned short)1, __ATOMIC_RELAXED, SCOPE_AGENT);

  const float* up_base = u + (size_t)(b0 + lr) * NT * NIN;
  f32x4 up0 = {0.f,0.f,0.f,0.f}, up1 = {0.f,0.f,0.f,0.f};
  if (lr < 8 && lg < 3) {
    up0 = *(const f32x4*)(up_base + lg * 8);
    up1 = *(const f32x4*)(up_base + lg * 8 + 4);
  }

  // poll: agent atomics (L3-coherent, fresh, deadlock-free). After detect:
  // fast -> one L1 buffer_inv (obs fresh in shared XCD L2); slow -> acq fence.
  auto group_wait = [&](unsigned tgt) {
    if (wave == 0) {
      for (;;) {
        unsigned x = __hip_atomic_load(&gf[lane & 7], __ATOMIC_RELAXED, SCOPE_AGENT);
        if (__all((int)(x >= tgt))) break;
        __builtin_amdgcn_s_sleep(1);
      }
      if (fast) asm volatile("buffer_inv" ::: "memory");
    }
    __syncthreads();
    if (!fast) __builtin_amdgcn_fence(__ATOMIC_ACQUIRE, "agent");
  };

  group_wait(1);

  // per-lane A base: rows >= 8 of the 16x16 A tile read the zero region
  const unsigned short* ab0 = (lr < 8) ? owbuf0 + lr * NN + lg * 8 : zreg + lg * 8;
  const unsigned short* ab1 = (lr < 8) ? ab0 + OBS_BUF_ELEMS : ab0;

  for (int t = 0; t < NT; ++t) {
    const unsigned short* ab = (t & 1) ? ab1 : ab0;
    unsigned short*       ow = (t & 1) ? owbuf0 : owbuf1;

    f32x4 acc  = {0.f, 0.f, 0.f, 0.f};
    f32x4 acc1 = {0.f, 0.f, 0.f, 0.f};

    // input term: A[row=lr][m] = u[b0+lr][t][m], zero-padded
    short8 ua;
    ua[0] = (short)f2bf(up0[0]); ua[1] = (short)f2bf(up0[1]);
    ua[2] = (short)f2bf(up0[2]); ua[3] = (short)f2bf(up0[3]);
    ua[4] = (short)f2bf(up1[0]); ua[5] = (short)f2bf(up1[1]);
    ua[6] = (short)f2bf(up1[2]); ua[7] = (short)f2bf(up1[3]);
    if (lr >= 8 || lg >= 3) ua = short8{0,0,0,0,0,0,0,0};
    acc = MF(ua, bin, acc);

    // recurrent GEMM: plain cacheable loads (fast: XCD-L2-resident obs)
#pragma unroll
    for (int kb = 0; kb < 32; kb += 2) {
      short8 a0 = *(const short8*)(ab + kb * 32);
      short8 a1 = *(const short8*)(ab + kb * 32 + 32);
      acc  = MF(a0, wf[kb],     acc);
      acc1 = MF(a1, wf[kb + 1], acc1);
    }

    // state update
    f32x4 rv;
#pragma unroll
    for (int q = 0; q < 4; ++q) {
      const float pre = acc[q] + acc1[q];
      const float act = 60.0f / (1.0f + expf(8.4f - 0.28f * pre)); // 30*(1+tanh(.14x-4.2))
      rv[q] = r[q] + (0.1f * (act - r[q])) * itau;
      r[q]  = rv[q];
    }

    if (t != NT - 1) {
      // release: obs stores -> vmcnt(0) (L2 ack only) -> barrier -> flag store
      if (lg < 2) {
#pragma unroll
        for (int q = 0; q < 4; ++q) {
          const unsigned short v = f2bf(rv[q] > 0.0f ? rv[q] : 0.0f);
          if (fast) ow[(lg * 4 + q) * NN + i] = v;
          else      __hip_atomic_store(&ow[(lg * 4 + q) * NN + i], v,
                                       __ATOMIC_RELAXED, SCOPE_AGENT);
        }
      }
      asm volatile("s_waitcnt vmcnt(0)" ::: "memory");
      __syncthreads();
      if (tid == 0)
        __hip_atomic_store(&gf[slot], (unsigned short)(t + 2),
                           __ATOMIC_RELAXED, SCOPE_AGENT);

      // off-critical-path (drains during the poll): u prefetch, out stores
      if (lr < 8 && lg < 3) {
        const float* up = up_base + (t + 1) * NIN + lg * 8;
        up0 = *(const f32x4*)(up);
        up1 = *(const f32x4*)(up + 4);
      }
      if (lg < 2) {
#pragma unroll
        for (int q = 0; q < 4; ++q)
          st_out(&out[((size_t)(b0 + lg * 4 + q) * NT + t) * NN + i], rv[q]);
      }

      group_wait((unsigned)(t + 2));
    } else {
      if (lg < 2) {
#pragma unroll
        for (int q = 0; q < 4; ++q)
          st_out(&out[((size_t)(b0 + lg * 4 + q) * NT + t) * NN + i], rv[q]);
      }
    }
  }

  // r_final
  if (lg < 2) {
#pragma unroll
    for (int q = 0; q < 4; ++q)
      out[(size_t)NBATCH * NT * NN + (size_t)(b0 + lg * 4 + q) * NN + i] = r[q];
  }
}

extern "C" void kernel_launch(void* const* d_in, const int* in_sizes, int n_in,
                              void* d_out, int out_size, void* d_ws, size_t ws_size,
                              hipStream_t stream) {
  const float* u   = (const float*)d_in[0];
  const float* r0  = (const float*)d_in[1];
  const float* W   = (const float*)d_in[2];
  const float* Bm  = (const float*)d_in[3];
  const float* tau = (const float*)d_in[4];
  const float* ds  = (const float*)d_in[5];
  float* out = (float*)d_out;

  unsigned*       arr      = (unsigned*)d_ws;
  unsigned*       xcd_cnt  = (unsigned*)((char*)d_ws + 512);
  unsigned*       ovf_cnt  = (unsigned*)((char*)d_ws + 576);
  unsigned*       grp_slow = (unsigned*)((char*)d_ws + 640);
  unsigned short* sflags   = (unsigned short*)((char*)d_ws + 1024);
  unsigned short* zreg     = (unsigned short*)((char*)d_ws + 4096);
  unsigned short* obs      = (unsigned short*)((char*)d_ws + 8192);

  // zero all control state every call (incl. graph replays -> deterministic)
  hipMemsetAsync(d_ws, 0, 8192, stream);

  rnn_step_all<<<dim3(NWG), dim3(512), 0, stream>>>(u, r0, W, Bm, tau, ds, out,
                                                    arr, xcd_cnt, ovf_cnt, grp_slow,
                                                    sflags, zreg, obs);
}